// Round 3
// baseline (38.729 us; speedup 1.0000x reference)
//
#include <hip/hip_runtime.h>
#include <hip/hip_bf16.h>
#include <stdint.h>

// B=2, L=256, CB=64, D=512, H=8, HD=64. BI = B*L = 512.
// Pipeline:
//   K0: MkT[hc][e] bf16, MvT[f][hc] bf16, Cb[hc] f32, bvoP[8][512] f32
//   G1: qkP[z] = (x @ Mk)*0.125 (+Cb*0.125 at z=0), split-K=2, fp32
//   K2: per (b,i): scores MFMA (A-frags direct from global pair, B-frags from qkP)
//       -> softmax (no max-sub) -> wp MFMA (Pt LDS, swizzled) -> wp bf16 via shfl-pack
//   G2: GP[z] = wp @ Mv  (split-K=2, pure GEMM)
//   K4: LayerNorm(GP0+GP1 + bo + sum_h bvoP + x)
//
// ws (float offsets): MkT@0(131072 u32) MvT@131072 Cb@262144 bvoP@262656
//   qkP@266752 (2x262144 f32, reused as GP)  wp@791040 (131072 u32)
//   total 922112 f32 = 3.7 MB

using u32   = unsigned int;
using s8bf  = __attribute__((ext_vector_type(8))) short;
using f32x4 = __attribute__((ext_vector_type(4))) float;

union U4 { uint4 u; s8bf v; };

__device__ __forceinline__ u32 pack2(float a, float b) {
  __hip_bfloat162 h2 = __float22bfloat162_rn(make_float2(a, b));
  union { __hip_bfloat162 h; u32 u; } cv; cv.h = h2; return cv.u;
}

// ---------------- K0: weight prep ----------------
__global__ __launch_bounds__(256) void k0_prep(
    const float* __restrict__ Wq, const float* __restrict__ bq,
    const float* __restrict__ Wk, const float* __restrict__ Wv,
    const float* __restrict__ Wo, const float* __restrict__ bv,
    u32* __restrict__ MkT, u32* __restrict__ MvT,
    float* __restrict__ Cb, float* __restrict__ bvoP) {
  __shared__ float LA[64][68];
  __shared__ float LB[64][68];
  __shared__ float bvec[64];
  const int t = threadIdx.x;
  const int bid = blockIdx.x;
  const bool isMk = bid < 64;
  const int sub = isMk ? bid : bid - 64;
  const int h = sub >> 3;
  const int tile = (sub & 7) * 64;

  for (int r = 0; r < 4; ++r) {
    int idx = t + 256 * r;
    int row = idx >> 4, dq = idx & 15;
    const float* src = isMk ? (Wq + (size_t)(tile + row) * 512 + h * 64 + dq * 4)
                            : (Wv + (size_t)row * 512 + h * 64 + dq * 4);
    float4 v = *(const float4*)src;
    LA[dq * 4 + 0][row] = v.x; LA[dq * 4 + 1][row] = v.y;
    LA[dq * 4 + 2][row] = v.z; LA[dq * 4 + 3][row] = v.w;
  }
  for (int r = 0; r < 4; ++r) {
    int idx = t + 256 * r;
    if (isMk) {
      int c = idx >> 4, dq = idx & 15;
      float4 v = *(const float4*)&Wk[(size_t)c * 512 + h * 64 + dq * 4];
      LB[dq * 4 + 0][c] = v.x; LB[dq * 4 + 1][c] = v.y;
      LB[dq * 4 + 2][c] = v.z; LB[dq * 4 + 3][c] = v.w;
    } else {
      int d = idx >> 4, fq = idx & 15;
      float4 v = *(const float4*)&Wo[(size_t)(h * 64 + d) * 512 + tile + fq * 4];
      *(float4*)&LB[d][fq * 4] = v;
    }
  }
  if (t < 16) {
    const float* bsrc = isMk ? bq : bv;
    float4 v = *(const float4*)&bsrc[h * 64 + t * 4];
    bvec[t * 4 + 0] = v.x; bvec[t * 4 + 1] = v.y;
    bvec[t * 4 + 2] = v.z; bvec[t * 4 + 3] = v.w;
  }
  __syncthreads();

  const int r0 = (t >> 4) * 4;
  const int c0 = (t & 15) * 4;
  float acc[4][4] = {};
  #pragma unroll 8
  for (int d = 0; d < 64; ++d) {
    float4 a = *(float4*)&LA[d][r0];
    float4 b = *(float4*)&LB[d][c0];
    acc[0][0] += a.x * b.x; acc[0][1] += a.x * b.y; acc[0][2] += a.x * b.z; acc[0][3] += a.x * b.w;
    acc[1][0] += a.y * b.x; acc[1][1] += a.y * b.y; acc[1][2] += a.y * b.z; acc[1][3] += a.y * b.w;
    acc[2][0] += a.z * b.x; acc[2][1] += a.z * b.y; acc[2][2] += a.z * b.z; acc[2][3] += a.z * b.w;
    acc[3][0] += a.w * b.x; acc[3][1] += a.w * b.y; acc[3][2] += a.w * b.z; acc[3][3] += a.w * b.w;
  }
  if (isMk) {
    #pragma unroll
    for (int j = 0; j < 4; ++j) {
      int hc = h * 64 + c0 + j;
      uint2 o = make_uint2(pack2(acc[0][j], acc[1][j]), pack2(acc[2][j], acc[3][j]));
      *(uint2*)&MkT[(size_t)hc * 256 + ((tile + r0) >> 1)] = o;
    }
    if ((sub & 7) == 0 && t < 64) {
      float s = 0.f;
      for (int d = 0; d < 64; ++d) s += bvec[d] * LB[d][t];
      Cb[h * 64 + t] = s;
    }
  } else {
    #pragma unroll
    for (int j = 0; j < 4; ++j) {
      int f = tile + c0 + j;
      uint2 o = make_uint2(pack2(acc[0][j], acc[1][j]), pack2(acc[2][j], acc[3][j]));
      *(uint2*)&MvT[(size_t)f * 256 + ((h * 64 + r0) >> 1)] = o;
    }
    if (t < 64) {
      float s = 0.f;
      for (int d = 0; d < 64; ++d) s += bvec[d] * LB[d][t];
      bvoP[h * 512 + tile + t] = s;
    }
  }
}

// ---------------- G1: qkP[z] = x @ Mk * 0.125 (+Cb*0.125 @ z0) ----------------
// grid (8 n, 8 m, 2 z), tile 64x64, K=256 single-shot.
__global__ __launch_bounds__(256) void k_g1(
    const float* __restrict__ x, const u32* __restrict__ MkT,
    const float* __restrict__ Cb, float* __restrict__ qkP) {
  __shared__ ushort As[64 * 264];
  __shared__ ushort Bs[64 * 264];
  const int t = threadIdx.x;
  const int n0 = blockIdx.x * 64, m0 = blockIdx.y * 64;
  const int kz = blockIdx.z, k0 = kz * 256;
  const int row = t >> 2, q = t & 3;
  {
    const float4* X4 = (const float4*)(x + (size_t)(m0 + row) * 512 + k0 + q * 64);
    #pragma unroll
    for (int i = 0; i < 8; ++i) {
      float4 a = X4[2 * i], b = X4[2 * i + 1];
      uint4 o = make_uint4(pack2(a.x, a.y), pack2(a.z, a.w),
                           pack2(b.x, b.y), pack2(b.z, b.w));
      *(uint4*)&As[row * 264 + q * 64 + i * 8] = o;
    }
    const uint4* B4 = (const uint4*)MkT;
    #pragma unroll
    for (int i = 0; i < 8; ++i) {
      uint4 v = B4[(size_t)(n0 + row) * 64 + kz * 32 + q * 8 + i];
      *(uint4*)&Bs[row * 264 + q * 64 + i * 8] = v;
    }
  }
  __syncthreads();
  const int lane = t & 63, w = t >> 6;
  const int lr = lane & 15, lg = lane >> 4;
  f32x4 acc[4] = {};
  #pragma unroll
  for (int kk = 0; kk < 8; ++kk) {
    U4 a; a.u = *(const uint4*)&As[(w * 16 + lr) * 264 + kk * 32 + lg * 8];
    #pragma unroll
    for (int nt = 0; nt < 4; ++nt) {
      U4 b; b.u = *(const uint4*)&Bs[(nt * 16 + lr) * 264 + kk * 32 + lg * 8];
      acc[nt] = __builtin_amdgcn_mfma_f32_16x16x32_bf16(a.v, b.v, acc[nt], 0, 0, 0);
    }
  }
  #pragma unroll
  for (int nt = 0; nt < 4; ++nt) {
    int n = n0 + nt * 16 + lr;
    float cb = (kz == 0) ? Cb[n] * 0.125f : 0.f;
    #pragma unroll
    for (int r = 0; r < 4; ++r)
      qkP[(size_t)kz * 262144 + (size_t)(m0 + w * 16 + lg * 4 + r) * 512 + n] =
          acc[nt][r] * 0.125f + cb;
  }
}

// ---------------- G2: GP[z] = wp @ Mv (pure GEMM) ----------------
__global__ __launch_bounds__(256) void k_g2(
    const u32* __restrict__ wp, const u32* __restrict__ MvT,
    float* __restrict__ GP) {
  __shared__ ushort As[64 * 264];
  __shared__ ushort Bs[64 * 264];
  const int t = threadIdx.x;
  const int n0 = blockIdx.x * 64, m0 = blockIdx.y * 64;
  const int kz = blockIdx.z;
  const int row = t >> 2, q = t & 3;
  {
    const uint4* A4 = (const uint4*)wp;
    const uint4* B4 = (const uint4*)MvT;
    #pragma unroll
    for (int i = 0; i < 8; ++i) {
      uint4 va = A4[(size_t)(m0 + row) * 64 + kz * 32 + q * 8 + i];
      *(uint4*)&As[row * 264 + q * 64 + i * 8] = va;
      uint4 vb = B4[(size_t)(n0 + row) * 64 + kz * 32 + q * 8 + i];
      *(uint4*)&Bs[row * 264 + q * 64 + i * 8] = vb;
    }
  }
  __syncthreads();
  const int lane = t & 63, w = t >> 6;
  const int lr = lane & 15, lg = lane >> 4;
  f32x4 acc[4] = {};
  #pragma unroll
  for (int kk = 0; kk < 8; ++kk) {
    U4 a; a.u = *(const uint4*)&As[(w * 16 + lr) * 264 + kk * 32 + lg * 8];
    #pragma unroll
    for (int nt = 0; nt < 4; ++nt) {
      U4 b; b.u = *(const uint4*)&Bs[(nt * 16 + lr) * 264 + kk * 32 + lg * 8];
      acc[nt] = __builtin_amdgcn_mfma_f32_16x16x32_bf16(a.v, b.v, acc[nt], 0, 0, 0);
    }
  }
  #pragma unroll
  for (int nt = 0; nt < 4; ++nt) {
    int n = n0 + nt * 16 + lr;
    #pragma unroll
    for (int r = 0; r < 4; ++r)
      GP[(size_t)kz * 262144 + (size_t)(m0 + w * 16 + lg * 4 + r) * 512 + n] = acc[nt][r];
  }
}

// ---------------- K2: scores -> softmax -> wp ----------------
__global__ __launch_bounds__(256) void k2_attn(
    const float* __restrict__ pair, const float* __restrict__ qkP,
    u32* __restrict__ wpg) {
  __shared__ u32 PtU[64 * 132];     // P^T[c][j-pairs], XOR-swizzled (33.8 KB)
  __shared__ ushort wb[16 * 264];   // weights bf16 [h][j] (8.4 KB)
  __shared__ float redz[16][4];     // per-h partial sums across waves
  const int t = threadIdx.x, bi = blockIdx.x;
  const int lane = t & 63, w = t >> 6;
  const int lr = lane & 15, lg = lane >> 4;
  const float* pr = pair + (size_t)bi * 16384;

  // ---- Pt staging: 256j x 64c fp32 -> bf16 transposed, swizzled ----
  #pragma unroll
  for (int r = 0; r < 8; ++r) {
    int task = t + 256 * r;
    int jp = task >> 4, cq = task & 15;
    const float* p0 = pr + (size_t)(2 * jp) * 64 + cq * 4;
    float4 a = *(const float4*)p0;
    float4 b = *(const float4*)(p0 + 64);
    int c = cq * 4;
    int col = jp ^ ((cq & 7) << 2);
    PtU[(c + 0) * 132 + col] = pack2(a.x, b.x);
    PtU[(c + 1) * 132 + col] = pack2(a.y, b.y);
    PtU[(c + 2) * 132 + col] = pack2(a.z, b.z);
    PtU[(c + 3) * 132 + col] = pack2(a.w, b.w);
  }

  // ---- scores B-frags from global qk (2 split-K slices) ----
  U4 bq0, bq1;
  bq0.u = make_uint4(0, 0, 0, 0); bq1.u = make_uint4(0, 0, 0, 0);
  if (lr < 8) {
    const float* q0 = qkP + (size_t)bi * 512 + lr * 64 + lg * 8;
    const float* q1 = q0 + 262144;
    float4 a0 = *(const float4*)q0,       a1 = *(const float4*)(q0 + 4);
    float4 c0 = *(const float4*)q1,       c1 = *(const float4*)(q1 + 4);
    float4 a2 = *(const float4*)(q0 + 32), a3 = *(const float4*)(q0 + 36);
    float4 c2 = *(const float4*)(q1 + 32), c3 = *(const float4*)(q1 + 36);
    bq0.u = make_uint4(pack2(a0.x + c0.x, a0.y + c0.y), pack2(a0.z + c0.z, a0.w + c0.w),
                       pack2(a1.x + c1.x, a1.y + c1.y), pack2(a1.z + c1.z, a1.w + c1.w));
    bq1.u = make_uint4(pack2(a2.x + c2.x, a2.y + c2.y), pack2(a2.z + c2.z, a2.w + c2.w),
                       pack2(a3.x + c3.x, a3.y + c3.y), pack2(a3.z + c3.z, a3.w + c3.w));
  }

  // ---- scores MFMA: wave w owns j in [w*64, w*64+64); A-frags direct from global ----
  f32x4 sc[4];
  #pragma unroll
  for (int jt = 0; jt < 4; ++jt) {
    const float* rp = pr + (size_t)(w * 64 + jt * 16 + lr) * 64 + lg * 8;
    float4 p0 = *(const float4*)rp;
    float4 p1 = *(const float4*)(rp + 4);
    float4 p2 = *(const float4*)(rp + 32);
    float4 p3 = *(const float4*)(rp + 36);
    U4 fa0, fa1;
    fa0.u = make_uint4(pack2(p0.x, p0.y), pack2(p0.z, p0.w),
                       pack2(p1.x, p1.y), pack2(p1.z, p1.w));
    fa1.u = make_uint4(pack2(p2.x, p2.y), pack2(p2.z, p2.w),
                       pack2(p3.x, p3.y), pack2(p3.z, p3.w));
    f32x4 z = {0.f, 0.f, 0.f, 0.f};
    z = __builtin_amdgcn_mfma_f32_16x16x32_bf16(fa0.v, bq0.v, z, 0, 0, 0);
    z = __builtin_amdgcn_mfma_f32_16x16x32_bf16(fa1.v, bq1.v, z, 0, 0, 0);
    sc[jt] = z;   // lane: h = lr, j = w*64 + jt*16 + lg*4 + reg
  }

  // ---- softmax over j per h (no max-sub: |s| small, fp32 exp safe) ----
  float ev[4][4];
  float es = 0.f;
  #pragma unroll
  for (int jt = 0; jt < 4; ++jt)
    #pragma unroll
    for (int r = 0; r < 4; ++r) { ev[jt][r] = __expf(sc[jt][r]); es += ev[jt][r]; }
  es += __shfl_xor(es, 16, 64);
  es += __shfl_xor(es, 32, 64);
  if (lane < 16) redz[lr][w] = es;
  __syncthreads();
  float4 zr = *(const float4*)&redz[lr][0];
  float rz = __builtin_amdgcn_rcpf(zr.x + zr.y + zr.z + zr.w);
  #pragma unroll
  for (int jt = 0; jt < 4; ++jt) {
    int j0 = w * 64 + jt * 16 + lg * 4;
    uint2 o = make_uint2(pack2(ev[jt][0] * rz, ev[jt][1] * rz),
                         pack2(ev[jt][2] * rz, ev[jt][3] * rz));
    *(uint2*)&wb[lr * 264 + j0] = o;
  }
  __syncthreads();

  // ---- wp MFMA: wave w owns c in [w*16, w*16+16) ----
  f32x4 wacc = {0.f, 0.f, 0.f, 0.f};
  const int c = w * 16 + lr;
  const int cswz = (c >> 2) & 7;
  #pragma unroll
  for (int ks = 0; ks < 8; ++ks) {
    U4 a; a.u = *(const uint4*)&wb[lr * 264 + ks * 32 + lg * 8];
    int g = ks * 4 + lg;
    U4 b; b.u = *(const uint4*)&PtU[c * 132 + ((g ^ cswz) << 2)];
    wacc = __builtin_amdgcn_mfma_f32_16x16x32_bf16(a.v, b.v, wacc, 0, 0, 0);
  }
  // lane holds wp[h = lg*4+r][c]; pack c-pairs via shfl and store (h<8 -> lane<32)
  float prt[4];
  #pragma unroll
  for (int r = 0; r < 4; ++r) prt[r] = __shfl_xor(wacc[r], 1, 64);
  if (lane < 32 && (lane & 1) == 0) {
    #pragma unroll
    for (int r = 0; r < 4; ++r) {
      int h = lg * 4 + r;
      wpg[(size_t)bi * 256 + h * 32 + (c >> 1)] = pack2(wacc[r], prt[r]);
    }
  }
}

// ---------------- K4: residual + biases + LayerNorm ----------------
__global__ __launch_bounds__(256) void k4_ln(
    const float* __restrict__ GP, const float* __restrict__ bvoP,
    const float* __restrict__ bo, const float* __restrict__ x,
    const float* __restrict__ gamma, const float* __restrict__ beta,
    float* __restrict__ out) {
  __shared__ float red[2][4];
  const int t = threadIdx.x, bi = blockIdx.x;
  const int f = t * 2;
  const size_t base = (size_t)bi * 512 + f;
  float2 y2 = *(const float2*)&GP[base];
  float2 g1 = *(const float2*)&GP[262144 + base];
  float2 xv = *(const float2*)&x[base];
  float2 bv2 = *(const float2*)&bo[f];
  y2.x += g1.x + xv.x + bv2.x; y2.y += g1.y + xv.y + bv2.y;
  #pragma unroll
  for (int h = 0; h < 8; ++h) {
    float2 bp = *(const float2*)&bvoP[h * 512 + f];
    y2.x += bp.x; y2.y += bp.y;
  }
  float s = y2.x + y2.y;
  float q = y2.x * y2.x + y2.y * y2.y;
  for (int o = 32; o; o >>= 1) { s += __shfl_xor(s, o, 64); q += __shfl_xor(q, o, 64); }
  const int wv = t >> 6, lane = t & 63;
  if (lane == 0) { red[0][wv] = s; red[1][wv] = q; }
  __syncthreads();
  float S = red[0][0] + red[0][1] + red[0][2] + red[0][3];
  float Qs = red[1][0] + red[1][1] + red[1][2] + red[1][3];
  float mu = S * (1.f / 512.f);
  float var = Qs * (1.f / 512.f) - mu * mu;
  float rstd = rsqrtf(var + 1e-5f);
  float2 gm = *(const float2*)&gamma[f];
  float2 bt = *(const float2*)&beta[f];
  float2 o2;
  o2.x = (y2.x - mu) * rstd * gm.x + bt.x;
  o2.y = (y2.y - mu) * rstd * gm.y + bt.y;
  *(float2*)&out[base] = o2;
}

extern "C" void kernel_launch(void* const* d_in, const int* in_sizes, int n_in,
                              void* d_out, int out_size, void* d_ws, size_t ws_size,
                              hipStream_t stream) {
  (void)in_sizes; (void)n_in; (void)out_size; (void)ws_size;
  const float* x     = (const float*)d_in[0];
  const float* pair  = (const float*)d_in[1];
  const float* Wq    = (const float*)d_in[2];
  const float* bq    = (const float*)d_in[3];
  const float* Wk    = (const float*)d_in[4];
  // d_in[5] = bk: Q.bk constant over j -> cancels in softmax
  const float* Wv    = (const float*)d_in[6];
  const float* bv    = (const float*)d_in[7];
  const float* Wo    = (const float*)d_in[8];
  const float* bo    = (const float*)d_in[9];
  const float* gamma = (const float*)d_in[10];
  const float* beta  = (const float*)d_in[11];

  float* ws   = (float*)d_ws;
  u32* MkT    = (u32*)ws;
  u32* MvT    = (u32*)ws + 131072;
  float* Cb   = ws + 262144;
  float* bvoP = ws + 262656;
  float* qkP  = ws + 266752;              // 2 slices; reused as GP by G2
  u32* wp     = (u32*)(ws + 791040);
  float* GP   = qkP;

  k0_prep<<<128, 256, 0, stream>>>(Wq, bq, Wk, Wv, Wo, bv, MkT, MvT, Cb, bvoP);
  k_g1<<<dim3(8, 8, 2), 256, 0, stream>>>(x, MkT, Cb, qkP);
  k2_attn<<<512, 256, 0, stream>>>(pair, qkP, wp);
  k_g2<<<dim3(8, 8, 2), 256, 0, stream>>>(wp, MvT, GP);
  k4_ln<<<512, 256, 0, stream>>>(GP, bvoP, bo, x, gamma, beta, (float*)d_out);
}

// Round 4
// 35.267 us; speedup vs baseline: 1.0982x; 1.0982x over previous
//
#include <hip/hip_runtime.h>
#include <hip/hip_bf16.h>
#include <stdint.h>

// B=2, L=256, CB=64, D=512, H=8, HD=64. BI = B*L = 512.
// Pipeline:
//   K0: MkT[hc][e] bf16, MvT[f][hc] bf16, Cb[hc] f32, bvoP[8][512] f32
//   G1: qkP[z] = (x @ Mk)*0.125 (+Cb*0.125 at z=0), split-K=4, fp32 partials
//   K2: per (b,i): pair staged ONCE to LDS (Pu row-major bf16 + Pt transposed
//       swizzled bf16) -> scores MFMA -> softmax (no max-sub) -> wp MFMA -> shfl-pack store
//   G2: GP[z] = wp @ Mv (split-K=4)
//   K4: LayerNorm(sum_z GP + bo + sum_h bvoP + x)
//
// ws (float offsets): MkT@0(131072 u32) MvT@131072 Cb@262144 bvoP@262656
//   qkP@266752 (4x262144 f32, reused as GP) wp@1315328 (131072 u32)

using u32   = unsigned int;
using s8bf  = __attribute__((ext_vector_type(8))) short;
using f32x4 = __attribute__((ext_vector_type(4))) float;

union U4 { uint4 u; s8bf v; };

__device__ __forceinline__ u32 pack2(float a, float b) {
  __hip_bfloat162 h2 = __float22bfloat162_rn(make_float2(a, b));
  union { __hip_bfloat162 h; u32 u; } cv; cv.h = h2; return cv.u;
}

// ---------------- K0: weight prep ----------------
__global__ __launch_bounds__(256) void k0_prep(
    const float* __restrict__ Wq, const float* __restrict__ bq,
    const float* __restrict__ Wk, const float* __restrict__ Wv,
    const float* __restrict__ Wo, const float* __restrict__ bv,
    u32* __restrict__ MkT, u32* __restrict__ MvT,
    float* __restrict__ Cb, float* __restrict__ bvoP) {
  __shared__ float LA[64][68];
  __shared__ float LB[64][68];
  __shared__ float bvec[64];
  const int t = threadIdx.x;
  const int bid = blockIdx.x;
  const bool isMk = bid < 64;
  const int sub = isMk ? bid : bid - 64;
  const int h = sub >> 3;
  const int tile = (sub & 7) * 64;

  for (int r = 0; r < 4; ++r) {
    int idx = t + 256 * r;
    int row = idx >> 4, dq = idx & 15;
    const float* src = isMk ? (Wq + (size_t)(tile + row) * 512 + h * 64 + dq * 4)
                            : (Wv + (size_t)row * 512 + h * 64 + dq * 4);
    float4 v = *(const float4*)src;
    LA[dq * 4 + 0][row] = v.x; LA[dq * 4 + 1][row] = v.y;
    LA[dq * 4 + 2][row] = v.z; LA[dq * 4 + 3][row] = v.w;
  }
  for (int r = 0; r < 4; ++r) {
    int idx = t + 256 * r;
    if (isMk) {
      int c = idx >> 4, dq = idx & 15;
      float4 v = *(const float4*)&Wk[(size_t)c * 512 + h * 64 + dq * 4];
      LB[dq * 4 + 0][c] = v.x; LB[dq * 4 + 1][c] = v.y;
      LB[dq * 4 + 2][c] = v.z; LB[dq * 4 + 3][c] = v.w;
    } else {
      int d = idx >> 4, fq = idx & 15;
      float4 v = *(const float4*)&Wo[(size_t)(h * 64 + d) * 512 + tile + fq * 4];
      *(float4*)&LB[d][fq * 4] = v;
    }
  }
  if (t < 16) {
    const float* bsrc = isMk ? bq : bv;
    float4 v = *(const float4*)&bsrc[h * 64 + t * 4];
    bvec[t * 4 + 0] = v.x; bvec[t * 4 + 1] = v.y;
    bvec[t * 4 + 2] = v.z; bvec[t * 4 + 3] = v.w;
  }
  __syncthreads();

  const int r0 = (t >> 4) * 4;
  const int c0 = (t & 15) * 4;
  float acc[4][4] = {};
  #pragma unroll 8
  for (int d = 0; d < 64; ++d) {
    float4 a = *(float4*)&LA[d][r0];
    float4 b = *(float4*)&LB[d][c0];
    acc[0][0] += a.x * b.x; acc[0][1] += a.x * b.y; acc[0][2] += a.x * b.z; acc[0][3] += a.x * b.w;
    acc[1][0] += a.y * b.x; acc[1][1] += a.y * b.y; acc[1][2] += a.y * b.z; acc[1][3] += a.y * b.w;
    acc[2][0] += a.z * b.x; acc[2][1] += a.z * b.y; acc[2][2] += a.z * b.z; acc[2][3] += a.z * b.w;
    acc[3][0] += a.w * b.x; acc[3][1] += a.w * b.y; acc[3][2] += a.w * b.z; acc[3][3] += a.w * b.w;
  }
  if (isMk) {
    #pragma unroll
    for (int j = 0; j < 4; ++j) {
      int hc = h * 64 + c0 + j;
      uint2 o = make_uint2(pack2(acc[0][j], acc[1][j]), pack2(acc[2][j], acc[3][j]));
      *(uint2*)&MkT[(size_t)hc * 256 + ((tile + r0) >> 1)] = o;
    }
    if ((sub & 7) == 0 && t < 64) {
      float s = 0.f;
      for (int d = 0; d < 64; ++d) s += bvec[d] * LB[d][t];
      Cb[h * 64 + t] = s;
    }
  } else {
    #pragma unroll
    for (int j = 0; j < 4; ++j) {
      int f = tile + c0 + j;
      uint2 o = make_uint2(pack2(acc[0][j], acc[1][j]), pack2(acc[2][j], acc[3][j]));
      *(uint2*)&MvT[(size_t)f * 256 + ((h * 64 + r0) >> 1)] = o;
    }
    if (t < 64) {
      float s = 0.f;
      for (int d = 0; d < 64; ++d) s += bvec[d] * LB[d][t];
      bvoP[h * 512 + tile + t] = s;
    }
  }
}

// ---------------- G1: qkP[z] = x @ Mk * 0.125 (+Cb*0.125 @ z0), split-K=4 ----------------
__global__ __launch_bounds__(256) void k_g1(
    const float* __restrict__ x, const u32* __restrict__ MkT,
    const float* __restrict__ Cb, float* __restrict__ qkP) {
  __shared__ ushort As[64 * 136];
  __shared__ ushort Bs[64 * 136];
  const int t = threadIdx.x;
  const int n0 = blockIdx.x * 64, m0 = blockIdx.y * 64;
  const int kz = blockIdx.z;
  const int row = t >> 2, q = t & 3;
  {
    const float* xp = x + (size_t)(m0 + row) * 512 + kz * 128 + q * 32;
    #pragma unroll
    for (int i = 0; i < 4; ++i) {
      float4 a = *(const float4*)(xp + i * 8);
      float4 b = *(const float4*)(xp + i * 8 + 4);
      uint4 o = make_uint4(pack2(a.x, a.y), pack2(a.z, a.w),
                           pack2(b.x, b.y), pack2(b.z, b.w));
      *(uint4*)&As[row * 136 + q * 32 + i * 8] = o;
    }
    const uint4* B4 = (const uint4*)MkT;
    #pragma unroll
    for (int i = 0; i < 4; ++i) {
      uint4 v = B4[(size_t)(n0 + row) * 64 + kz * 16 + q * 4 + i];
      *(uint4*)&Bs[row * 136 + q * 32 + i * 8] = v;
    }
  }
  __syncthreads();
  const int lane = t & 63, w = t >> 6;
  const int lr = lane & 15, lg = lane >> 4;
  f32x4 acc[4] = {};
  #pragma unroll
  for (int kk = 0; kk < 4; ++kk) {
    U4 a; a.u = *(const uint4*)&As[(w * 16 + lr) * 136 + kk * 32 + lg * 8];
    #pragma unroll
    for (int nt = 0; nt < 4; ++nt) {
      U4 b; b.u = *(const uint4*)&Bs[(nt * 16 + lr) * 136 + kk * 32 + lg * 8];
      acc[nt] = __builtin_amdgcn_mfma_f32_16x16x32_bf16(a.v, b.v, acc[nt], 0, 0, 0);
    }
  }
  #pragma unroll
  for (int nt = 0; nt < 4; ++nt) {
    int n = n0 + nt * 16 + lr;
    float cb = (kz == 0) ? Cb[n] * 0.125f : 0.f;
    #pragma unroll
    for (int r = 0; r < 4; ++r)
      qkP[(size_t)kz * 262144 + (size_t)(m0 + w * 16 + lg * 4 + r) * 512 + n] =
          acc[nt][r] * 0.125f + cb;
  }
}

// ---------------- G2: GP[z] = wp @ Mv, split-K=4 ----------------
__global__ __launch_bounds__(256) void k_g2(
    const u32* __restrict__ wp, const u32* __restrict__ MvT,
    float* __restrict__ GP) {
  __shared__ ushort As[64 * 136];
  __shared__ ushort Bs[64 * 136];
  const int t = threadIdx.x;
  const int n0 = blockIdx.x * 64, m0 = blockIdx.y * 64;
  const int kz = blockIdx.z;
  const int row = t >> 2, q = t & 3;
  {
    const uint4* A4 = (const uint4*)wp;
    const uint4* B4 = (const uint4*)MvT;
    #pragma unroll
    for (int i = 0; i < 4; ++i) {
      uint4 va = A4[(size_t)(m0 + row) * 64 + kz * 16 + q * 4 + i];
      *(uint4*)&As[row * 136 + q * 32 + i * 8] = va;
      uint4 vb = B4[(size_t)(n0 + row) * 64 + kz * 16 + q * 4 + i];
      *(uint4*)&Bs[row * 136 + q * 32 + i * 8] = vb;
    }
  }
  __syncthreads();
  const int lane = t & 63, w = t >> 6;
  const int lr = lane & 15, lg = lane >> 4;
  f32x4 acc[4] = {};
  #pragma unroll
  for (int kk = 0; kk < 4; ++kk) {
    U4 a; a.u = *(const uint4*)&As[(w * 16 + lr) * 136 + kk * 32 + lg * 8];
    #pragma unroll
    for (int nt = 0; nt < 4; ++nt) {
      U4 b; b.u = *(const uint4*)&Bs[(nt * 16 + lr) * 136 + kk * 32 + lg * 8];
      acc[nt] = __builtin_amdgcn_mfma_f32_16x16x32_bf16(a.v, b.v, acc[nt], 0, 0, 0);
    }
  }
  #pragma unroll
  for (int nt = 0; nt < 4; ++nt) {
    int n = n0 + nt * 16 + lr;
    #pragma unroll
    for (int r = 0; r < 4; ++r)
      GP[(size_t)kz * 262144 + (size_t)(m0 + w * 16 + lg * 4 + r) * 512 + n] = acc[nt][r];
  }
}

// ---------------- K2: scores -> softmax -> wp (pair read ONCE) ----------------
__global__ __launch_bounds__(256) void k2_attn(
    const float* __restrict__ pair, const float* __restrict__ qkP,
    u32* __restrict__ wpg) {
  __shared__ u32 PuU[256 * 36];     // pair bf16 [j][c-pairs], 36.9 KB; wb overlays after scores
  __shared__ u32 PtU[64 * 132];     // pair^T bf16 [c][j-pairs], XOR-swizzled, 33.8 KB
  __shared__ float redz[16][4];
  const int t = threadIdx.x, bi = blockIdx.x;
  const int lane = t & 63, w = t >> 6;
  const int lr = lane & 15, lg = lane >> 4;
  const float* pr = pair + (size_t)bi * 16384;

  // ---- stage pair once: row-major Pu + transposed swizzled Pt ----
  #pragma unroll
  for (int r = 0; r < 8; ++r) {
    int task = t + 256 * r;
    int jp = task >> 4, cq = task & 15;
    const float* p0 = pr + (size_t)(2 * jp) * 64 + cq * 4;
    float4 a = *(const float4*)p0;
    float4 b = *(const float4*)(p0 + 64);
    *(uint2*)&PuU[(2 * jp) * 36 + cq * 2]     = make_uint2(pack2(a.x, a.y), pack2(a.z, a.w));
    *(uint2*)&PuU[(2 * jp + 1) * 36 + cq * 2] = make_uint2(pack2(b.x, b.y), pack2(b.z, b.w));
    int c = cq * 4;
    int col = jp ^ ((cq & 7) << 2);
    PtU[(c + 0) * 132 + col] = pack2(a.x, b.x);
    PtU[(c + 1) * 132 + col] = pack2(a.y, b.y);
    PtU[(c + 2) * 132 + col] = pack2(a.z, b.z);
    PtU[(c + 3) * 132 + col] = pack2(a.w, b.w);
  }

  // ---- qk B-frags from global (4 split-K slices), overlap with staging ----
  U4 bq0, bq1;
  bq0.u = make_uint4(0, 0, 0, 0); bq1.u = make_uint4(0, 0, 0, 0);
  if (lr < 8) {
    const float* q0 = qkP + (size_t)bi * 512 + lr * 64 + lg * 8;
    float4 a0 = *(const float4*)q0,        a1 = *(const float4*)(q0 + 4);
    float4 a2 = *(const float4*)(q0 + 32), a3 = *(const float4*)(q0 + 36);
    #pragma unroll
    for (int z = 1; z < 4; ++z) {
      const float* qz = q0 + (size_t)z * 262144;
      float4 c0 = *(const float4*)qz,        c1 = *(const float4*)(qz + 4);
      float4 c2 = *(const float4*)(qz + 32), c3 = *(const float4*)(qz + 36);
      a0.x += c0.x; a0.y += c0.y; a0.z += c0.z; a0.w += c0.w;
      a1.x += c1.x; a1.y += c1.y; a1.z += c1.z; a1.w += c1.w;
      a2.x += c2.x; a2.y += c2.y; a2.z += c2.z; a2.w += c2.w;
      a3.x += c3.x; a3.y += c3.y; a3.z += c3.z; a3.w += c3.w;
    }
    bq0.u = make_uint4(pack2(a0.x, a0.y), pack2(a0.z, a0.w),
                       pack2(a1.x, a1.y), pack2(a1.z, a1.w));
    bq1.u = make_uint4(pack2(a2.x, a2.y), pack2(a2.z, a2.w),
                       pack2(a3.x, a3.y), pack2(a3.z, a3.w));
  }
  __syncthreads();

  // ---- scores MFMA: wave w owns j in [w*64, w*64+64), A-frags from Pu LDS ----
  f32x4 sc[4];
  #pragma unroll
  for (int jt = 0; jt < 4; ++jt) {
    int j0 = w * 64 + jt * 16;
    U4 a0, a1;
    a0.u = *(const uint4*)&PuU[(j0 + lr) * 36 + lg * 4];
    a1.u = *(const uint4*)&PuU[(j0 + lr) * 36 + 16 + lg * 4];
    f32x4 z = {0.f, 0.f, 0.f, 0.f};
    z = __builtin_amdgcn_mfma_f32_16x16x32_bf16(a0.v, bq0.v, z, 0, 0, 0);
    z = __builtin_amdgcn_mfma_f32_16x16x32_bf16(a1.v, bq1.v, z, 0, 0, 0);
    sc[jt] = z;   // lane: h = lr, j = j0 + lg*4 + reg
  }

  // ---- softmax over j per h (no max-sub: |s| ~ N(0,1/9)) ----
  float ev[4][4];
  float es = 0.f;
  #pragma unroll
  for (int jt = 0; jt < 4; ++jt)
    #pragma unroll
    for (int r = 0; r < 4; ++r) { ev[jt][r] = __expf(sc[jt][r]); es += ev[jt][r]; }
  es += __shfl_xor(es, 16, 64);
  es += __shfl_xor(es, 32, 64);
  if (lane < 16) redz[lr][w] = es;
  __syncthreads();
  float4 zr = *(const float4*)&redz[lr][0];
  float rz = __builtin_amdgcn_rcpf(zr.x + zr.y + zr.z + zr.w);
  // weights overlay Pu (all Pu reads completed before the redz barrier)
  ushort* wb = (ushort*)PuU;
  #pragma unroll
  for (int jt = 0; jt < 4; ++jt) {
    int j0 = w * 64 + jt * 16 + lg * 4;
    uint2 o = make_uint2(pack2(ev[jt][0] * rz, ev[jt][1] * rz),
                         pack2(ev[jt][2] * rz, ev[jt][3] * rz));
    *(uint2*)&wb[lr * 264 + j0] = o;
  }
  __syncthreads();

  // ---- wp MFMA: wave w owns c in [w*16, w*16+16) ----
  f32x4 wacc = {0.f, 0.f, 0.f, 0.f};
  const int c = w * 16 + lr;
  const int cswz = (c >> 2) & 7;
  #pragma unroll
  for (int ks = 0; ks < 8; ++ks) {
    U4 a; a.u = *(const uint4*)&wb[lr * 264 + ks * 32 + lg * 8];
    int g = ks * 4 + lg;
    U4 b; b.u = *(const uint4*)&PtU[c * 132 + ((g ^ cswz) << 2)];
    wacc = __builtin_amdgcn_mfma_f32_16x16x32_bf16(a.v, b.v, wacc, 0, 0, 0);
  }
  // lane holds wp[h = lg*4+r][c]; shfl-pack c-pairs, store (h<8 -> lane<32)
  float prt[4];
  #pragma unroll
  for (int r = 0; r < 4; ++r) prt[r] = __shfl_xor(wacc[r], 1, 64);
  if (lane < 32 && (lane & 1) == 0) {
    #pragma unroll
    for (int r = 0; r < 4; ++r) {
      int h = lg * 4 + r;
      wpg[(size_t)bi * 256 + h * 32 + (c >> 1)] = pack2(wacc[r], prt[r]);
    }
  }
}

// ---------------- K4: residual + biases + LayerNorm ----------------
__global__ __launch_bounds__(256) void k4_ln(
    const float* __restrict__ GP, const float* __restrict__ bvoP,
    const float* __restrict__ bo, const float* __restrict__ x,
    const float* __restrict__ gamma, const float* __restrict__ beta,
    float* __restrict__ out) {
  __shared__ float red[2][4];
  const int t = threadIdx.x, bi = blockIdx.x;
  const int f = t * 2;
  const size_t base = (size_t)bi * 512 + f;
  float2 y2 = *(const float2*)&GP[base];
  #pragma unroll
  for (int z = 1; z < 4; ++z) {
    float2 g = *(const float2*)&GP[(size_t)z * 262144 + base];
    y2.x += g.x; y2.y += g.y;
  }
  float2 xv = *(const float2*)&x[base];
  float2 bv2 = *(const float2*)&bo[f];
  y2.x += xv.x + bv2.x; y2.y += xv.y + bv2.y;
  #pragma unroll
  for (int h = 0; h < 8; ++h) {
    float2 bp = *(const float2*)&bvoP[h * 512 + f];
    y2.x += bp.x; y2.y += bp.y;
  }
  float s = y2.x + y2.y;
  float q = y2.x * y2.x + y2.y * y2.y;
  for (int o = 32; o; o >>= 1) { s += __shfl_xor(s, o, 64); q += __shfl_xor(q, o, 64); }
  const int wv = t >> 6, lane = t & 63;
  if (lane == 0) { red[0][wv] = s; red[1][wv] = q; }
  __syncthreads();
  float S = red[0][0] + red[0][1] + red[0][2] + red[0][3];
  float Qs = red[1][0] + red[1][1] + red[1][2] + red[1][3];
  float mu = S * (1.f / 512.f);
  float var = Qs * (1.f / 512.f) - mu * mu;
  float rstd = rsqrtf(var + 1e-5f);
  float2 gm = *(const float2*)&gamma[f];
  float2 bt = *(const float2*)&beta[f];
  float2 o2;
  o2.x = (y2.x - mu) * rstd * gm.x + bt.x;
  o2.y = (y2.y - mu) * rstd * gm.y + bt.y;
  *(float2*)&out[base] = o2;
}

extern "C" void kernel_launch(void* const* d_in, const int* in_sizes, int n_in,
                              void* d_out, int out_size, void* d_ws, size_t ws_size,
                              hipStream_t stream) {
  (void)in_sizes; (void)n_in; (void)out_size; (void)ws_size;
  const float* x     = (const float*)d_in[0];
  const float* pair  = (const float*)d_in[1];
  const float* Wq    = (const float*)d_in[2];
  const float* bq    = (const float*)d_in[3];
  const float* Wk    = (const float*)d_in[4];
  // d_in[5] = bk: Q.bk constant over j -> cancels in softmax
  const float* Wv    = (const float*)d_in[6];
  const float* bv    = (const float*)d_in[7];
  const float* Wo    = (const float*)d_in[8];
  const float* bo    = (const float*)d_in[9];
  const float* gamma = (const float*)d_in[10];
  const float* beta  = (const float*)d_in[11];

  float* ws   = (float*)d_ws;
  u32* MkT    = (u32*)ws;
  u32* MvT    = (u32*)ws + 131072;
  float* Cb   = ws + 262144;
  float* bvoP = ws + 262656;
  float* qkP  = ws + 266752;              // 4 slices; reused as GP by G2
  u32* wp     = (u32*)(ws + 1315328);
  float* GP   = qkP;

  k0_prep<<<128, 256, 0, stream>>>(Wq, bq, Wk, Wv, Wo, bv, MkT, MvT, Cb, bvoP);
  k_g1<<<dim3(8, 8, 4), 256, 0, stream>>>(x, MkT, Cb, qkP);
  k2_attn<<<512, 256, 0, stream>>>(pair, qkP, wp);
  k_g2<<<dim3(8, 8, 4), 256, 0, stream>>>(wp, MvT, GP);
  k4_ln<<<512, 256, 0, stream>>>(GP, bvoP, bo, x, gamma, beta, (float*)d_out);
}

// Round 5
// 32.552 us; speedup vs baseline: 1.1898x; 1.0834x over previous
//
#include <hip/hip_runtime.h>
#include <hip/hip_bf16.h>
#include <stdint.h>

// B=2, L=256, CB=64, D=512, H=8, HD=64. BI = B*L = 512.
// Pipeline:
//   K0 (MFMA): MkT[hc][e] bf16 (pre-scaled by 0.125), MvT[f][hc] bf16,
//              Cb[hc] f32 (pre-scaled), bvoP[8][512] f32
//   G1: qkP[z] = x @ Mk_scaled (+Cb at z=0), split-K=4, tile 32x64, 512 blocks
//   K2: per (b,i): pair staged ONCE to LDS -> scores MFMA -> softmax (no max-sub)
//       -> wp MFMA -> shfl-pack bf16 store
//   G2: GP[z] = wp @ Mv, split-K=4, tile 32x64, 512 blocks
//   K4: LayerNorm(sum_z GP + bo + sum_h bvoP + x)
//
// ws (float offsets): MkT@0(131072 u32) MvT@131072 Cb@262144 bvoP@262656
//   qkP@266752 (4x262144 f32, reused as GP) wp@1315328 (131072 u32)

using u32   = unsigned int;
using s8bf  = __attribute__((ext_vector_type(8))) short;
using f32x4 = __attribute__((ext_vector_type(4))) float;

union U4 { uint4 u; s8bf v; };

__device__ __forceinline__ u32 pack2(float a, float b) {
  __hip_bfloat162 h2 = __float22bfloat162_rn(make_float2(a, b));
  union { __hip_bfloat162 h; u32 u; } cv; cv.h = h2; return cv.u;
}
__device__ __forceinline__ ushort bf16r(float f) {
  u32 u = __float_as_uint(f);
  return (ushort)((u + 0x7fffu + ((u >> 16) & 1u)) >> 16);
}
__device__ __forceinline__ float ubf(ushort s) {
  return __uint_as_float(((u32)s) << 16);
}

// ---------------- K0: weight prep (MFMA bf16) ----------------
// blocks 0..63: Mk (h = sub>>3, e-tile = (sub&7)*64), scaled 0.125
// blocks 64..127: Mv (h, f-tile)
__global__ __launch_bounds__(256) void k0_prep(
    const float* __restrict__ Wq, const float* __restrict__ bq,
    const float* __restrict__ Wk, const float* __restrict__ Wv,
    const float* __restrict__ Wo, const float* __restrict__ bv,
    u32* __restrict__ MkT, u32* __restrict__ MvT,
    float* __restrict__ Cb, float* __restrict__ bvoP) {
  __shared__ ushort LA[64 * 72];   // [row][d] bf16 (Mk: Wq-tile rows e; Mv: Wv rows c)
  __shared__ ushort LB[64 * 72];   // [row][d] bf16 (Mk: Wk rows c; Mv: Wo^T rows f)
  __shared__ float bvec[64];
  const int t = threadIdx.x;
  const int bid = blockIdx.x;
  const bool isMk = bid < 64;
  const int sub = isMk ? bid : bid - 64;
  const int h = sub >> 3;
  const int tile = (sub & 7) * 64;

  { // LA: 64 rows x 64 d, fp32 -> bf16 (rows d-contiguous in global)
    int row = t >> 2, q = t & 3;
    const float* Arow = isMk ? (Wq + (size_t)(tile + row) * 512 + h * 64)
                             : (Wv + (size_t)row * 512 + h * 64);
    #pragma unroll
    for (int i = 0; i < 4; ++i) {
      int d0 = q * 4 + i * 16;
      float4 v = *(const float4*)(Arow + d0);
      *(uint2*)&LA[row * 72 + d0] = make_uint2(pack2(v.x, v.y), pack2(v.z, v.w));
    }
  }
  if (isMk) {   // LB = Wk rows c (d-contiguous)
    int row = t >> 2, q = t & 3;
    const float* Brow = Wk + (size_t)row * 512 + h * 64;
    #pragma unroll
    for (int i = 0; i < 4; ++i) {
      int d0 = q * 4 + i * 16;
      float4 v = *(const float4*)(Brow + d0);
      *(uint2*)&LB[row * 72 + d0] = make_uint2(pack2(v.x, v.y), pack2(v.z, v.w));
    }
  } else {      // LB = Wo^T rows f: read Wo[hd][f] f-contig, scatter-write [f][d]
    int d = t >> 2, q = t & 3;
    const float* Brow = Wo + (size_t)(h * 64 + d) * 512 + tile;
    #pragma unroll
    for (int i = 0; i < 4; ++i) {
      int f0 = q * 4 + i * 16;
      float4 v = *(const float4*)(Brow + f0);
      LB[(f0 + 0) * 72 + d] = bf16r(v.x);
      LB[(f0 + 1) * 72 + d] = bf16r(v.y);
      LB[(f0 + 2) * 72 + d] = bf16r(v.z);
      LB[(f0 + 3) * 72 + d] = bf16r(v.w);
    }
  }
  if (t < 16) {
    const float* bsrc = isMk ? bq : bv;
    float4 v = *(const float4*)&bsrc[h * 64 + t * 4];
    bvec[t * 4 + 0] = v.x; bvec[t * 4 + 1] = v.y;
    bvec[t * 4 + 2] = v.z; bvec[t * 4 + 3] = v.w;
  }
  __syncthreads();

  const int lane = t & 63, w = t >> 6;
  const int lr = lane & 15, lg = lane >> 4;
  f32x4 acc[4] = {};
  #pragma unroll
  for (int kk = 0; kk < 2; ++kk) {
    U4 a; a.u = *(const uint4*)&LA[(w * 16 + lr) * 72 + kk * 32 + lg * 8];
    #pragma unroll
    for (int nt = 0; nt < 4; ++nt) {
      U4 b; b.u = *(const uint4*)&LB[(nt * 16 + lr) * 72 + kk * 32 + lg * 8];
      acc[nt] = __builtin_amdgcn_mfma_f32_16x16x32_bf16(a.v, b.v, acc[nt], 0, 0, 0);
    }
  }
  // acc[nt][r] = C[m = w*16 + lg*4 + r][n = nt*16 + lr],  C = A.B^T over d
  if (isMk) {
    // Mk[e][c] * 0.125 -> MkT[hc][e]
    #pragma unroll
    for (int nt = 0; nt < 4; ++nt) {
      int hc = h * 64 + nt * 16 + lr;
      int e0 = tile + w * 16 + lg * 4;
      uint2 o = make_uint2(pack2(acc[nt][0] * 0.125f, acc[nt][1] * 0.125f),
                           pack2(acc[nt][2] * 0.125f, acc[nt][3] * 0.125f));
      *(uint2*)&MkT[(size_t)hc * 256 + (e0 >> 1)] = o;
    }
    if ((sub & 7) == 0 && t < 64) {
      float s = 0.f;
      #pragma unroll 16
      for (int d = 0; d < 64; ++d) s += bvec[d] * ubf(LB[t * 72 + d]);
      Cb[h * 64 + t] = s * 0.125f;
    }
  } else {
    // Mv[hc][f] -> MvT[f][hc]
    #pragma unroll
    for (int nt = 0; nt < 4; ++nt) {
      int f = tile + nt * 16 + lr;
      int hc0 = h * 64 + w * 16 + lg * 4;
      uint2 o = make_uint2(pack2(acc[nt][0], acc[nt][1]),
                           pack2(acc[nt][2], acc[nt][3]));
      *(uint2*)&MvT[(size_t)f * 256 + (hc0 >> 1)] = o;
    }
    if (t < 64) {
      float s = 0.f;
      #pragma unroll 16
      for (int d = 0; d < 64; ++d) s += bvec[d] * ubf(LB[t * 72 + d]);
      bvoP[h * 512 + tile + t] = s;
    }
  }
}

// ---------------- G1: qkP[z] = x @ Mk_s (+Cb @ z0), tile 32x64, split-K=4 ----------------
// grid (8 n, 16 m, 4 z) = 512 blocks
__global__ __launch_bounds__(256) void k_g1(
    const float* __restrict__ x, const u32* __restrict__ MkT,
    const float* __restrict__ Cb, float* __restrict__ qkP) {
  __shared__ ushort As[32 * 136];
  __shared__ ushort Bs[64 * 136];
  const int t = threadIdx.x;
  const int n0 = blockIdx.x * 64, m0 = blockIdx.y * 32;
  const int kz = blockIdx.z;
  { // A: 32 rows x 128 k fp32 -> bf16, coalesced 128B/row per instruction
    int row = t >> 3, q = t & 7;
    const float* xp = x + (size_t)(m0 + row) * 512 + kz * 128;
    #pragma unroll
    for (int i = 0; i < 4; ++i) {
      int d0 = q * 4 + i * 32;
      float4 v = *(const float4*)(xp + d0);
      *(uint2*)&As[row * 136 + d0] = make_uint2(pack2(v.x, v.y), pack2(v.z, v.w));
    }
  }
  { // B: 64 rows x 128 k bf16 (16 uint4/row)
    int row = t >> 2, q = t & 3;
    const uint4* B4 = (const uint4*)MkT + (size_t)(n0 + row) * 64 + kz * 16;
    #pragma unroll
    for (int i = 0; i < 4; ++i) {
      uint4 v = B4[q * 4 + i];
      *(uint4*)&Bs[row * 136 + q * 32 + i * 8] = v;
    }
  }
  __syncthreads();
  const int lane = t & 63, w = t >> 6;
  const int lr = lane & 15, lg = lane >> 4;
  const int mh = w & 1, nh = w >> 1;
  f32x4 acc[2] = {};
  #pragma unroll
  for (int kk = 0; kk < 4; ++kk) {
    U4 a; a.u = *(const uint4*)&As[(mh * 16 + lr) * 136 + kk * 32 + lg * 8];
    #pragma unroll
    for (int nt = 0; nt < 2; ++nt) {
      U4 b; b.u = *(const uint4*)&Bs[(nh * 32 + nt * 16 + lr) * 136 + kk * 32 + lg * 8];
      acc[nt] = __builtin_amdgcn_mfma_f32_16x16x32_bf16(a.v, b.v, acc[nt], 0, 0, 0);
    }
  }
  #pragma unroll
  for (int nt = 0; nt < 2; ++nt) {
    int n = n0 + nh * 32 + nt * 16 + lr;
    float cb = (kz == 0) ? Cb[n] : 0.f;
    #pragma unroll
    for (int r = 0; r < 4; ++r)
      qkP[(size_t)kz * 262144 + (size_t)(m0 + mh * 16 + lg * 4 + r) * 512 + n] =
          acc[nt][r] + cb;
  }
}

// ---------------- G2: GP[z] = wp @ Mv, tile 32x64, split-K=4 ----------------
__global__ __launch_bounds__(256) void k_g2(
    const u32* __restrict__ wp, const u32* __restrict__ MvT,
    float* __restrict__ GP) {
  __shared__ ushort As[32 * 136];
  __shared__ ushort Bs[64 * 136];
  const int t = threadIdx.x;
  const int n0 = blockIdx.x * 64, m0 = blockIdx.y * 32;
  const int kz = blockIdx.z;
  { // A: wp bf16, 32 rows x 16 uint4
    int row = t >> 3, q = t & 7;
    const uint4* A4 = (const uint4*)wp + (size_t)(m0 + row) * 64 + kz * 16;
    #pragma unroll
    for (int i = 0; i < 2; ++i) {
      uint4 v = A4[q * 2 + i];
      *(uint4*)&As[row * 136 + q * 16 + i * 8] = v;
    }
  }
  {
    int row = t >> 2, q = t & 3;
    const uint4* B4 = (const uint4*)MvT + (size_t)(n0 + row) * 64 + kz * 16;
    #pragma unroll
    for (int i = 0; i < 4; ++i) {
      uint4 v = B4[q * 4 + i];
      *(uint4*)&Bs[row * 136 + q * 32 + i * 8] = v;
    }
  }
  __syncthreads();
  const int lane = t & 63, w = t >> 6;
  const int lr = lane & 15, lg = lane >> 4;
  const int mh = w & 1, nh = w >> 1;
  f32x4 acc[2] = {};
  #pragma unroll
  for (int kk = 0; kk < 4; ++kk) {
    U4 a; a.u = *(const uint4*)&As[(mh * 16 + lr) * 136 + kk * 32 + lg * 8];
    #pragma unroll
    for (int nt = 0; nt < 2; ++nt) {
      U4 b; b.u = *(const uint4*)&Bs[(nh * 32 + nt * 16 + lr) * 136 + kk * 32 + lg * 8];
      acc[nt] = __builtin_amdgcn_mfma_f32_16x16x32_bf16(a.v, b.v, acc[nt], 0, 0, 0);
    }
  }
  #pragma unroll
  for (int nt = 0; nt < 2; ++nt) {
    int n = n0 + nh * 32 + nt * 16 + lr;
    #pragma unroll
    for (int r = 0; r < 4; ++r)
      GP[(size_t)kz * 262144 + (size_t)(m0 + mh * 16 + lg * 4 + r) * 512 + n] = acc[nt][r];
  }
}

// ---------------- K2: scores -> softmax -> wp (pair read ONCE) ----------------
__global__ __launch_bounds__(256) void k2_attn(
    const float* __restrict__ pair, const float* __restrict__ qkP,
    u32* __restrict__ wpg) {
  __shared__ u32 PuU[256 * 36];     // pair bf16 [j][c-pairs]; wb overlays after scores
  __shared__ u32 PtU[64 * 132];     // pair^T bf16 [c][j-pairs], XOR-swizzled
  __shared__ float redz[16][4];
  const int t = threadIdx.x, bi = blockIdx.x;
  const int lane = t & 63, w = t >> 6;
  const int lr = lane & 15, lg = lane >> 4;
  const float* pr = pair + (size_t)bi * 16384;

  // ---- stage pair once: row-major Pu + transposed swizzled Pt ----
  #pragma unroll
  for (int r = 0; r < 8; ++r) {
    int task = t + 256 * r;
    int jp = task >> 4, cq = task & 15;
    const float* p0 = pr + (size_t)(2 * jp) * 64 + cq * 4;
    float4 a = *(const float4*)p0;
    float4 b = *(const float4*)(p0 + 64);
    *(uint2*)&PuU[(2 * jp) * 36 + cq * 2]     = make_uint2(pack2(a.x, a.y), pack2(a.z, a.w));
    *(uint2*)&PuU[(2 * jp + 1) * 36 + cq * 2] = make_uint2(pack2(b.x, b.y), pack2(b.z, b.w));
    int c = cq * 4;
    int col = jp ^ ((cq & 7) << 2);
    PtU[(c + 0) * 132 + col] = pack2(a.x, b.x);
    PtU[(c + 1) * 132 + col] = pack2(a.y, b.y);
    PtU[(c + 2) * 132 + col] = pack2(a.z, b.z);
    PtU[(c + 3) * 132 + col] = pack2(a.w, b.w);
  }

  // ---- qk B-frags from global (4 split-K slices), overlap with staging ----
  U4 bq0, bq1;
  bq0.u = make_uint4(0, 0, 0, 0); bq1.u = make_uint4(0, 0, 0, 0);
  if (lr < 8) {
    const float* q0 = qkP + (size_t)bi * 512 + lr * 64 + lg * 8;
    float4 a0 = *(const float4*)q0,        a1 = *(const float4*)(q0 + 4);
    float4 a2 = *(const float4*)(q0 + 32), a3 = *(const float4*)(q0 + 36);
    #pragma unroll
    for (int z = 1; z < 4; ++z) {
      const float* qz = q0 + (size_t)z * 262144;
      float4 c0 = *(const float4*)qz,        c1 = *(const float4*)(qz + 4);
      float4 c2 = *(const float4*)(qz + 32), c3 = *(const float4*)(qz + 36);
      a0.x += c0.x; a0.y += c0.y; a0.z += c0.z; a0.w += c0.w;
      a1.x += c1.x; a1.y += c1.y; a1.z += c1.z; a1.w += c1.w;
      a2.x += c2.x; a2.y += c2.y; a2.z += c2.z; a2.w += c2.w;
      a3.x += c3.x; a3.y += c3.y; a3.z += c3.z; a3.w += c3.w;
    }
    bq0.u = make_uint4(pack2(a0.x, a0.y), pack2(a0.z, a0.w),
                       pack2(a1.x, a1.y), pack2(a1.z, a1.w));
    bq1.u = make_uint4(pack2(a2.x, a2.y), pack2(a2.z, a2.w),
                       pack2(a3.x, a3.y), pack2(a3.z, a3.w));
  }
  __syncthreads();

  // ---- scores MFMA: wave w owns j in [w*64, w*64+64), A-frags from Pu LDS ----
  f32x4 sc[4];
  #pragma unroll
  for (int jt = 0; jt < 4; ++jt) {
    int j0 = w * 64 + jt * 16;
    U4 a0, a1;
    a0.u = *(const uint4*)&PuU[(j0 + lr) * 36 + lg * 4];
    a1.u = *(const uint4*)&PuU[(j0 + lr) * 36 + 16 + lg * 4];
    f32x4 z = {0.f, 0.f, 0.f, 0.f};
    z = __builtin_amdgcn_mfma_f32_16x16x32_bf16(a0.v, bq0.v, z, 0, 0, 0);
    z = __builtin_amdgcn_mfma_f32_16x16x32_bf16(a1.v, bq1.v, z, 0, 0, 0);
    sc[jt] = z;   // lane: h = lr, j = j0 + lg*4 + reg
  }

  // ---- softmax over j per h (no max-sub: |s| ~ N(0,1/9)) ----
  float ev[4][4];
  float es = 0.f;
  #pragma unroll
  for (int jt = 0; jt < 4; ++jt)
    #pragma unroll
    for (int r = 0; r < 4; ++r) { ev[jt][r] = __expf(sc[jt][r]); es += ev[jt][r]; }
  es += __shfl_xor(es, 16, 64);
  es += __shfl_xor(es, 32, 64);
  if (lane < 16) redz[lr][w] = es;
  __syncthreads();
  float4 zr = *(const float4*)&redz[lr][0];
  float rz = __builtin_amdgcn_rcpf(zr.x + zr.y + zr.z + zr.w);
  // weights overlay Pu (all Pu reads completed before the redz barrier)
  ushort* wb = (ushort*)PuU;
  #pragma unroll
  for (int jt = 0; jt < 4; ++jt) {
    int j0 = w * 64 + jt * 16 + lg * 4;
    uint2 o = make_uint2(pack2(ev[jt][0] * rz, ev[jt][1] * rz),
                         pack2(ev[jt][2] * rz, ev[jt][3] * rz));
    *(uint2*)&wb[lr * 264 + j0] = o;
  }
  __syncthreads();

  // ---- wp MFMA: wave w owns c in [w*16, w*16+16) ----
  f32x4 wacc = {0.f, 0.f, 0.f, 0.f};
  const int c = w * 16 + lr;
  const int cswz = (c >> 2) & 7;
  #pragma unroll
  for (int ks = 0; ks < 8; ++ks) {
    U4 a; a.u = *(const uint4*)&wb[lr * 264 + ks * 32 + lg * 8];
    int g = ks * 4 + lg;
    U4 b; b.u = *(const uint4*)&PtU[c * 132 + ((g ^ cswz) << 2)];
    wacc = __builtin_amdgcn_mfma_f32_16x16x32_bf16(a.v, b.v, wacc, 0, 0, 0);
  }
  // lane holds wp[h = lg*4+r][c]; shfl-pack c-pairs, store (h<8 -> lane<32)
  float prt[4];
  #pragma unroll
  for (int r = 0; r < 4; ++r) prt[r] = __shfl_xor(wacc[r], 1, 64);
  if (lane < 32 && (lane & 1) == 0) {
    #pragma unroll
    for (int r = 0; r < 4; ++r) {
      int h = lg * 4 + r;
      wpg[(size_t)bi * 256 + h * 32 + (c >> 1)] = pack2(wacc[r], prt[r]);
    }
  }
}

// ---------------- K4: residual + biases + LayerNorm ----------------
__global__ __launch_bounds__(256) void k4_ln(
    const float* __restrict__ GP, const float* __restrict__ bvoP,
    const float* __restrict__ bo, const float* __restrict__ x,
    const float* __restrict__ gamma, const float* __restrict__ beta,
    float* __restrict__ out) {
  __shared__ float red[2][4];
  const int t = threadIdx.x, bi = blockIdx.x;
  const int f = t * 2;
  const size_t base = (size_t)bi * 512 + f;
  float2 y2 = *(const float2*)&GP[base];
  #pragma unroll
  for (int z = 1; z < 4; ++z) {
    float2 g = *(const float2*)&GP[(size_t)z * 262144 + base];
    y2.x += g.x; y2.y += g.y;
  }
  float2 xv = *(const float2*)&x[base];
  float2 bv2 = *(const float2*)&bo[f];
  y2.x += xv.x + bv2.x; y2.y += xv.y + bv2.y;
  #pragma unroll
  for (int h = 0; h < 8; ++h) {
    float2 bp = *(const float2*)&bvoP[h * 512 + f];
    y2.x += bp.x; y2.y += bp.y;
  }
  float s = y2.x + y2.y;
  float q = y2.x * y2.x + y2.y * y2.y;
  for (int o = 32; o; o >>= 1) { s += __shfl_xor(s, o, 64); q += __shfl_xor(q, o, 64); }
  const int wv = t >> 6, lane = t & 63;
  if (lane == 0) { red[0][wv] = s; red[1][wv] = q; }
  __syncthreads();
  float S = red[0][0] + red[0][1] + red[0][2] + red[0][3];
  float Qs = red[1][0] + red[1][1] + red[1][2] + red[1][3];
  float mu = S * (1.f / 512.f);
  float var = Qs * (1.f / 512.f) - mu * mu;
  float rstd = rsqrtf(var + 1e-5f);
  float2 gm = *(const float2*)&gamma[f];
  float2 bt = *(const float2*)&beta[f];
  float2 o2;
  o2.x = (y2.x - mu) * rstd * gm.x + bt.x;
  o2.y = (y2.y - mu) * rstd * gm.y + bt.y;
  *(float2*)&out[base] = o2;
}

extern "C" void kernel_launch(void* const* d_in, const int* in_sizes, int n_in,
                              void* d_out, int out_size, void* d_ws, size_t ws_size,
                              hipStream_t stream) {
  (void)in_sizes; (void)n_in; (void)out_size; (void)ws_size;
  const float* x     = (const float*)d_in[0];
  const float* pair  = (const float*)d_in[1];
  const float* Wq    = (const float*)d_in[2];
  const float* bq    = (const float*)d_in[3];
  const float* Wk    = (const float*)d_in[4];
  // d_in[5] = bk: Q.bk constant over j -> cancels in softmax
  const float* Wv    = (const float*)d_in[6];
  const float* bv    = (const float*)d_in[7];
  const float* Wo    = (const float*)d_in[8];
  const float* bo    = (const float*)d_in[9];
  const float* gamma = (const float*)d_in[10];
  const float* beta  = (const float*)d_in[11];

  float* ws   = (float*)d_ws;
  u32* MkT    = (u32*)ws;
  u32* MvT    = (u32*)ws + 131072;
  float* Cb   = ws + 262144;
  float* bvoP = ws + 262656;
  float* qkP  = ws + 266752;              // 4 slices; reused as GP by G2
  u32* wp     = (u32*)(ws + 1315328);
  float* GP   = qkP;

  k0_prep<<<128, 256, 0, stream>>>(Wq, bq, Wk, Wv, Wo, bv, MkT, MvT, Cb, bvoP);
  k_g1<<<dim3(8, 16, 4), 256, 0, stream>>>(x, MkT, Cb, qkP);
  k2_attn<<<512, 256, 0, stream>>>(pair, qkP, wp);
  k_g2<<<dim3(8, 16, 4), 256, 0, stream>>>(wp, MvT, GP);
  k4_ln<<<512, 256, 0, stream>>>(GP, bvoP, bo, x, gamma, beta, (float*)d_out);
}